// Round 3
// baseline (297.594 us; speedup 1.0000x reference)
//
#include <hip/hip_runtime.h>
#include <hip/hip_fp16.h>

#define IN_CH 256
#define OUT_CH 8

typedef float  f32x4 __attribute__((ext_vector_type(4)));
typedef unsigned int u32x4 __attribute__((ext_vector_type(4)));

// ---------------------------------------------------------------------------
// Projection: P1 = X @ W1^T, P2 = X @ W2^T, stored as packed f16 (8 halves =
// 16 B per node per table) so both tables (3.2 MB total) fit each XCD's 4 MiB
// L2 during the gather.
// Thread (node = gid>>3, o = gid&7). No LDS: lanes 0-7 read the same X row
// (same-address dedup -> one transaction), W rows are L1-resident (16 KB).
// ---------------------------------------------------------------------------
__global__ __launch_bounds__(256) void proj_kernel(
    const float* __restrict__ X,
    const float* __restrict__ W1,
    const float* __restrict__ W2,
    __half* __restrict__ P1h,
    __half* __restrict__ P2h,
    int n)
{
    const int gid  = blockIdx.x * 256 + threadIdx.x;
    const int node = gid >> 3;
    const int o    = gid & 7;
    if (node >= n) return;

    const float4* xr = (const float4*)(X + (size_t)node * IN_CH);
    const float4* w1 = (const float4*)(W1 + o * IN_CH);
    const float4* w2 = (const float4*)(W2 + o * IN_CH);

    float a1 = 0.f, a2 = 0.f;
    #pragma unroll 8
    for (int k = 0; k < IN_CH / 4; ++k) {
        float4 x = xr[k];
        float4 u = w1[k];
        float4 v = w2[k];
        a1 += x.x * u.x + x.y * u.y + x.z * u.z + x.w * u.w;
        a2 += x.x * v.x + x.y * v.y + x.z * v.z + x.w * v.w;
    }

    // gid == node*8 + o -> contiguous 2-B stores per block
    P1h[gid] = __float2half(a1);
    P2h[gid] = __float2half(a2);
}

// ---------------------------------------------------------------------------
// Gather: out[e] = toF32(T1[e0[e]]) + toF32(T2[e1[e]])
// Table reads cached (L2-resident); index loads and output stores are
// nontemporal so the 256 MB of streaming traffic doesn't evict the tables.
// ---------------------------------------------------------------------------
__global__ __launch_bounds__(256) void gather_kernel(
    const int* __restrict__ e0,
    const int* __restrict__ e1,
    const uint4* __restrict__ T1,   // [n] x 8 halves
    const uint4* __restrict__ T2,
    f32x4* __restrict__ outv,       // [E*2] float4 (native vec for nt store)
    int E, int n)
{
    const int stride = gridDim.x * 256;
    const unsigned nmax = (unsigned)(n - 1);
    for (int e = blockIdx.x * 256 + threadIdx.x; e < E; e += stride) {
        unsigned i0 = (unsigned)__builtin_nontemporal_load(e0 + e);
        unsigned i1 = (unsigned)__builtin_nontemporal_load(e1 + e);
        i0 = i0 > nmax ? nmax : i0;   // defensive clamp (no-op for valid input)
        i1 = i1 > nmax ? nmax : i1;

        uint4 a = T1[i0];
        uint4 b = T2[i1];
        const __half2* ah = (const __half2*)&a;
        const __half2* bh = (const __half2*)&b;

        float2 s0 = __half22float2(ah[0]);
        float2 s1 = __half22float2(ah[1]);
        float2 s2 = __half22float2(ah[2]);
        float2 s3 = __half22float2(ah[3]);
        float2 t0 = __half22float2(bh[0]);
        float2 t1 = __half22float2(bh[1]);
        float2 t2 = __half22float2(bh[2]);
        float2 t3 = __half22float2(bh[3]);

        f32x4 r0 = { s0.x + t0.x, s0.y + t0.y, s1.x + t1.x, s1.y + t1.y };
        f32x4 r1 = { s2.x + t2.x, s2.y + t2.y, s3.x + t3.x, s3.y + t3.y };

        size_t oi = 2u * (size_t)e;
        __builtin_nontemporal_store(r0, outv + oi);
        __builtin_nontemporal_store(r1, outv + oi + 1);
    }
}

extern "C" void kernel_launch(void* const* d_in, const int* in_sizes, int n_in,
                              void* d_out, int out_size, void* d_ws, size_t ws_size,
                              hipStream_t stream) {
    const float* X    = (const float*)d_in[0];
    const int*   eidx = (const int*)d_in[1];
    const float* W1   = (const float*)d_in[2];
    const float* W2   = (const float*)d_in[3];

    const int n = in_sizes[0] / IN_CH;   // 100000
    const int E = in_sizes[1] / 2;       // 6400000

    __half* P1h = (__half*)d_ws;                    // [n*8] f16 = 1.6 MB
    __half* P2h = P1h + (size_t)n * OUT_CH;         // [n*8] f16 = 1.6 MB

    const int proj_blocks = (n * OUT_CH + 255) / 256;   // 3125
    proj_kernel<<<proj_blocks, 256, 0, stream>>>(X, W1, W2, P1h, P2h, n);

    const int gather_blocks = (E + 255) / 256;          // 25000, 1 edge/thread
    gather_kernel<<<gather_blocks, 256, 0, stream>>>(
        eidx, eidx + E, (const uint4*)P1h, (const uint4*)P2h,
        (f32x4*)d_out, E, n);
}

// Round 4
// 149.336 us; speedup vs baseline: 1.9928x; 1.9928x over previous
//
#include <hip/hip_runtime.h>
#include <hip/hip_fp16.h>

#define IN_CH 256
#define OUT_CH 8
#define CHUNK 32            // k-floats per chunk
#define NCHUNK (IN_CH / CHUNK)
#define ROWSTRIDE 36        // 32 + 4 pad floats: spreads bank windows

typedef float f32x4 __attribute__((ext_vector_type(4)));

__device__ __forceinline__ unsigned pack2h(float a, float b) {
    __half2 h = __floats2half2_rn(a, b);
    return *(unsigned*)&h;
}

// ---------------------------------------------------------------------------
// Projection: P1 = X @ W1^T, P2 = X @ W2^T -> packed f16 tables (16 B/node).
// Per-WAVE tiling, no block barriers: wave owns 64 nodes + its own LDS slice.
// Per k-chunk: coalesced global->LDS (transpose), lane pulls its node's 32
// floats to VGPRs once, W comes from wave-uniform scalar loads (s_load).
// ---------------------------------------------------------------------------
__global__ __launch_bounds__(256) void proj_kernel(
    const float* __restrict__ X,
    const float* __restrict__ W1,
    const float* __restrict__ W2,
    uint4* __restrict__ P1v,        // [n] packed 8xf16
    uint4* __restrict__ P2v,
    int n)
{
    __shared__ float Xs[4][64][ROWSTRIDE];

    const int wave = threadIdx.x >> 6;
    const int lane = threadIdx.x & 63;
    const int base = blockIdx.x * 256 + wave * 64;   // wave's first node
    if (base >= n) return;                            // whole wave out of range

    const bool full = (base + 64 <= n);

    float acc1[OUT_CH];
    float acc2[OUT_CH];
    #pragma unroll
    for (int o = 0; o < OUT_CH; ++o) { acc1[o] = 0.f; acc2[o] = 0.f; }

    const float4* W1v = (const float4*)W1;   // [8][64] float4
    const float4* W2v = (const float4*)W2;

    for (int c = 0; c < NCHUNK; ++c) {
        // ---- stage: 64 rows x 32 floats = 512 float4, 8 per lane, coalesced
        #pragma unroll
        for (int j = 0; j < 8; ++j) {
            const int idx = lane + 64 * j;       // 0..511
            const int row = idx >> 3;            // 0..63
            const int q   = idx & 7;             // float4 within chunk
            float4 v = make_float4(0.f, 0.f, 0.f, 0.f);
            if (full || base + row < n)
                v = *(const float4*)(X + (size_t)(base + row) * IN_CH + c * CHUNK + q * 4);
            *(float4*)&Xs[wave][row][q * 4] = v;
        }
        // same-wave LDS write->read: compiler inserts lgkmcnt wait, no barrier

        // ---- pull this lane's node row (32 floats) into registers
        float4 xq[8];
        #pragma unroll
        for (int q = 0; q < 8; ++q)
            xq[q] = *(const float4*)&Xs[wave][lane][q * 4];

        // ---- 16 dot products, W via wave-uniform (scalar) loads
        #pragma unroll
        for (int o = 0; o < OUT_CH; ++o) {
            float s1 = 0.f, s2 = 0.f;
            #pragma unroll
            for (int q = 0; q < 8; ++q) {
                float4 w1 = W1v[o * 64 + c * 8 + q];
                float4 w2 = W2v[o * 64 + c * 8 + q];
                float4 x  = xq[q];
                s1 += x.x * w1.x + x.y * w1.y + x.z * w1.z + x.w * w1.w;
                s2 += x.x * w2.x + x.y * w2.y + x.z * w2.z + x.w * w2.w;
            }
            acc1[o] += s1;
            acc2[o] += s2;
        }
    }

    const int node = base + lane;
    if (node < n) {
        uint4 p1, p2;
        p1.x = pack2h(acc1[0], acc1[1]); p1.y = pack2h(acc1[2], acc1[3]);
        p1.z = pack2h(acc1[4], acc1[5]); p1.w = pack2h(acc1[6], acc1[7]);
        p2.x = pack2h(acc2[0], acc2[1]); p2.y = pack2h(acc2[2], acc2[3]);
        p2.z = pack2h(acc2[4], acc2[5]); p2.w = pack2h(acc2[6], acc2[7]);
        P1v[node] = p1;                  // lane-consecutive 16B -> coalesced
        P2v[node] = p2;
    }
}

// ---------------------------------------------------------------------------
// Gather: out[e] = toF32(T1[e0[e]]) + toF32(T2[e1[e]])
// Tables (3.2 MB f16) stay L2-resident; index loads and output stores are
// nontemporal so 256 MB of streaming traffic doesn't evict them.
// ---------------------------------------------------------------------------
__global__ __launch_bounds__(256) void gather_kernel(
    const int* __restrict__ e0,
    const int* __restrict__ e1,
    const uint4* __restrict__ T1,
    const uint4* __restrict__ T2,
    f32x4* __restrict__ outv,
    int E, int n)
{
    const int stride = gridDim.x * 256;
    const unsigned nmax = (unsigned)(n - 1);
    for (int e = blockIdx.x * 256 + threadIdx.x; e < E; e += stride) {
        unsigned i0 = (unsigned)__builtin_nontemporal_load(e0 + e);
        unsigned i1 = (unsigned)__builtin_nontemporal_load(e1 + e);
        i0 = i0 > nmax ? nmax : i0;
        i1 = i1 > nmax ? nmax : i1;

        uint4 a = T1[i0];
        uint4 b = T2[i1];
        const __half2* ah = (const __half2*)&a;
        const __half2* bh = (const __half2*)&b;

        float2 s0 = __half22float2(ah[0]);
        float2 s1 = __half22float2(ah[1]);
        float2 s2 = __half22float2(ah[2]);
        float2 s3 = __half22float2(ah[3]);
        float2 t0 = __half22float2(bh[0]);
        float2 t1 = __half22float2(bh[1]);
        float2 t2 = __half22float2(bh[2]);
        float2 t3 = __half22float2(bh[3]);

        f32x4 r0 = { s0.x + t0.x, s0.y + t0.y, s1.x + t1.x, s1.y + t1.y };
        f32x4 r1 = { s2.x + t2.x, s2.y + t2.y, s3.x + t3.x, s3.y + t3.y };

        size_t oi = 2u * (size_t)e;
        __builtin_nontemporal_store(r0, outv + oi);
        __builtin_nontemporal_store(r1, outv + oi + 1);
    }
}

extern "C" void kernel_launch(void* const* d_in, const int* in_sizes, int n_in,
                              void* d_out, int out_size, void* d_ws, size_t ws_size,
                              hipStream_t stream) {
    const float* X    = (const float*)d_in[0];
    const int*   eidx = (const int*)d_in[1];
    const float* W1   = (const float*)d_in[2];
    const float* W2   = (const float*)d_in[3];

    const int n = in_sizes[0] / IN_CH;   // 100000
    const int E = in_sizes[1] / 2;       // 6400000

    uint4* P1v = (uint4*)d_ws;                        // [n] x 16B = 1.6 MB
    uint4* P2v = P1v + n;                             // [n] x 16B = 1.6 MB

    const int proj_blocks = (n + 255) / 256;          // 391 (256 nodes/block)
    proj_kernel<<<proj_blocks, 256, 0, stream>>>(X, W1, W2, P1v, P2v, n);

    const int gather_blocks = (E + 255) / 256;        // 25000, 1 edge/thread
    gather_kernel<<<gather_blocks, 256, 0, stream>>>(
        eidx, eidx + E, (const uint4*)P1v, (const uint4*)P2v,
        (f32x4*)d_out, E, n);
}